// Round 9
// baseline (1251.495 us; speedup 1.0000x reference)
//
#include <hip/hip_runtime.h>
#include <hip/hip_bf16.h>

typedef __attribute__((ext_vector_type(8))) short short8;
typedef float f32x4 __attribute__((ext_vector_type(4)));
typedef unsigned long long u64;

#define DIM 512
#define HID 2048
#define ROWSZ (513*512)
#define DT 0.0625f

#define WAITV(n) asm volatile("s_waitcnt vmcnt(" #n ")" ::: "memory")
#define SBAR()   asm volatile("s_barrier" ::: "memory")
typedef const __attribute__((address_space(1))) void* gas1;
typedef __attribute__((address_space(3))) void* las3;
// aux=1 -> SC0: bypass L1, served by XCD L2 (mutable, same-XCD producer); aux=0 -> weights (L1 ok)
#define GLL16(g,l,aux) __builtin_amdgcn_global_load_lds((gas1)(g),(las3)(l),16,0,aux)
#define GLL4(g,l,aux)  __builtin_amdgcn_global_load_lds((gas1)(g),(las3)(l),4,0,aux)

__device__ __forceinline__ float bf2f(unsigned short s){ return __uint_as_float(((unsigned)s)<<16); }
__device__ __forceinline__ unsigned short f2bfu(float f){ __hip_bfloat16 h=__float2bfloat16(f); return *(unsigned short*)&h; }
__device__ __forceinline__ float dot8(uint4 wq, const float* a){
  const unsigned short* ws=(const unsigned short*)&wq;
  float s=0.f;
#pragma unroll
  for(int i=0;i<8;++i) s += bf2f(ws[i])*a[i];
  return s;
}

// XCD barrier: 32 wgs, relaxed agent atomics, no cache maintenance
__device__ __forceinline__ void xbar(int* arr, int* gen, int target, bool lead){
  asm volatile("s_waitcnt vmcnt(0) lgkmcnt(0)" ::: "memory");
  __syncthreads();
  if (threadIdx.x == 0){
    __hip_atomic_fetch_add(arr, 1, __ATOMIC_RELAXED, __HIP_MEMORY_SCOPE_AGENT);
    if (lead){
      while (__hip_atomic_load(arr, __ATOMIC_RELAXED, __HIP_MEMORY_SCOPE_AGENT) < 32*target)
        __builtin_amdgcn_s_sleep(2);
      __hip_atomic_store(gen, target, __ATOMIC_RELAXED, __HIP_MEMORY_SCOPE_AGENT);
    } else {
      while (__hip_atomic_load(gen, __ATOMIC_RELAXED, __HIP_MEMORY_SCOPE_AGENT) < target)
        __builtin_amdgcn_s_sleep(4);
    }
  }
  __syncthreads();
}

__global__ void k_transpose_bf16(const float* __restrict__ src,
                                 __hip_bfloat16* __restrict__ dst, int R, int C) {
  __shared__ float tile[32][33];
  int c0 = blockIdx.x * 32, r0 = blockIdx.y * 32;
  int tx = threadIdx.x & 31, ty = threadIdx.x >> 5;
  for (int i = 0; i < 32; i += 8)
    tile[ty + i][tx] = src[(size_t)(r0 + ty + i) * C + c0 + tx];
  __syncthreads();
  for (int i = 0; i < 32; i += 8)
    dst[(size_t)(c0 + ty + i) * R + r0 + tx] = __float2bfloat16(tile[tx][ty + i]);
}

__global__ __launch_bounds__(512, 2) void k_persist(
    const float* __restrict__ y0, const float* __restrict__ Dy0,
    const unsigned short* __restrict__ W1t, const unsigned short* __restrict__ W2t,
    const float* __restrict__ b1, const float* __restrict__ b2,
    unsigned short* __restrict__ Vbuf, unsigned short* __restrict__ tbuf,
    float* __restrict__ yts, float* __restrict__ a_ss, float* __restrict__ pbuf,
    int* __restrict__ ctrl, float* __restrict__ out) {
  // ring: 8 bufs x 16KB. Phase A: A tile 64x64 @[0..4095], B 64x64 @[4096..8191]
  //       Phase B: A 64x64 @[0..4095], B 32x64 @[4096..6143]
  __shared__ __align__(16) short tiles[8][8192];    // 128 KB
  __shared__ float ytL[DIM];                        // 2 KB
  __shared__ float asL[1024];                       // 4 KB (kq half of a)
  __shared__ float paccL[512];                      // 2 KB
  __shared__ float c1L[64], c2L[64];
  __shared__ int bcast[2];
  // ~136.5 KB -> 1 wg/CU -> exactly 32 wg/XCD

  const int t = threadIdx.x;
  if (t == 0) {
    int x;
    asm volatile("s_getreg_b32 %0, hwreg(HW_REG_XCC_ID)" : "=s"(x));
    x &= 7;
    bcast[0] = x;
    bcast[1] = atomicAdd(&ctrl[x], 1);
  }
  __syncthreads();
  const int xcd = bcast[0];
  const int sl  = bcast[1] & 31;
  const bool lead = (sl == 0);
  int* arr = ctrl + 64 + xcd * 64;
  int* gen = arr + 32;

  const int w = t >> 6, lane = t & 63, quad = lane >> 4, l16 = lane & 15;
  const int l7 = l16 & 7;
  const int mX = xcd * 64;
  const int nA = sl * 64;                   // phase A col tile (64 of 2048)
  const int ni = sl >> 1, kq = sl & 1;      // phase B: 16 n-tiles x 2 K-halves
  const int nB = ni * 32;
  const int kb = kq * 1024;
  float* ytx = yts + xcd * DIM;
  float* asx = a_ss + xcd * HID;
  float* rec = pbuf + (size_t)(xcd * 16 + ni) * 2112;
  int* flg = ctrl + 576 + xcd * 16 + ni;

  // phase A wave layout: 2m x 4n (wave tile 32x16)
  const int awm = (w & 1) * 32, awn = (w >> 1) * 16;
  // phase B wave layout: 4m x 2n (wave tile 16x16)
  const int bwm = (w >> 1) * 16, bwn = (w & 1) * 16;
  const int r8 = lane >> 3;

  // persistent state (kq==0 wgs): Dy tile 64x32, 4 elems/thread
  f32x4 DyR = {0.f,0.f,0.f,0.f}, K1 = DyR, K2 = DyR, K3 = DyR;
  float yR = 0.f, kd1 = 0.f, kd2 = 0.f, kd3 = 0.f;
  const int erow0 = mX + bwm + quad * 4;    // global Dy row base for this thread
  const int ecol  = nB + bwn + l16;         // global Dy col

  auto issueA = [&](int buf, int c) {
    short* tA = &tiles[buf][0];
    short* tB = &tiles[buf][4096];
    int k0 = c * 64;
    int gsw = ((lane & 7) ^ r8) * 8;
    GLL16(Vbuf + (size_t)(mX + w * 8 + r8) * DIM + k0 + gsw, tA + (w * 8) * 64, 1);
    GLL16(W1t + (size_t)(nA + w * 8 + r8) * DIM + k0 + gsw,  tB + (w * 8) * 64, 0);
  };
  auto issueB = [&](int buf, int c) {
    short* tA = &tiles[buf][0];
    short* tB = &tiles[buf][4096];
    int k0 = kb + c * 64;
    int gsw = ((lane & 7) ^ r8) * 8;
    GLL16(tbuf + (size_t)(mX + w * 8 + r8) * HID + k0 + gsw, tA + (w * 8) * 64, 1);
    if (lane < 32) {
      int r4 = lane >> 3;
      int gw = ((lane & 7) ^ ((w * 4 + r4) & 7)) * 8;
      GLL16(W2t + (size_t)(nB + w * 4 + r4) * HID + k0 + gw, tB + (w * 4) * 64, 0);
    }
  };

  // ---- init ----
  if (kq == 0) {
#pragma unroll
    for (int r = 0; r < 4; ++r) {
      float v = Dy0[(size_t)(erow0 + r) * DIM + ecol];
      DyR[r] = v;
      Vbuf[(size_t)(erow0 + r) * DIM + ecol] = f2bfu(v);
      out[DIM + (size_t)(erow0 + r) * DIM + ecol] = v;
    }
    if (t < 32) {
      float v = y0[nB + t];
      yR = v;
      ytx[nB + t] = v;
      if (xcd == 0) out[nB + t] = v;
    }
  }
  int barid = 1;
  xbar(arr, gen, barid++, lead);

  for (int ss = 0; ss < 16; ++ss) {
    for (int st = 0; st < 4; ++st) {
      const float cn = (st == 2) ? DT : 0.5f * DT;
      const int seq = ss * 4 + st + 1;
      // ========== PHASE A: g = V @ W1t^T (+ fused h-matvec, no redundancy) ==========
      {
        GLL4(ytx + w * 64 + lane, &ytL[w * 64], 1);
        issueA(0, 0); issueA(1, 1); issueA(2, 2);
        issueA(3, 3); issueA(4, 4); issueA(5, 5);
        f32x4 acc0 = {0.f,0.f,0.f,0.f}, acc1 = acc0;
        float hs = 0.f;
#pragma unroll
        for (int c = 0; c < 8; ++c) {
          if (c < 2) issueA(c + 6, c + 6);
          if (c < 3)      { WAITV(12); }
          else if (c == 3){ WAITV(8); }
          else if (c == 4){ WAITV(6); }
          else if (c == 5){ WAITV(4); }
          else if (c == 6){ WAITV(2); }
          else            { WAITV(0); }
          SBAR();
          const short* tA = &tiles[c & 7][0];
          const short* tB = &tiles[c & 7][4096];
#pragma unroll
          for (int kk = 0; kk < 64; kk += 32) {
            int lg = (kk >> 3) + quad;
            int pa0 = (awm + l16), pa1 = (awm + 16 + l16), pb = (awn + l16);
            short8 a0 = *(const short8*)&tA[pa0 * 64 + ((lg ^ (pa0 & 7)) << 3)];
            short8 a1 = *(const short8*)&tA[pa1 * 64 + ((lg ^ (pa1 & 7)) << 3)];
            short8 b  = *(const short8*)&tB[pb * 64 + ((lg ^ (pb & 7)) << 3)];
            acc0 = __builtin_amdgcn_mfma_f32_16x16x32_bf16(a0, b, acc0, 0, 0, 0);
            acc1 = __builtin_amdgcn_mfma_f32_16x16x32_bf16(a1, b, acc1, 0, 0, 0);
          }
          {
            int ph = (w ^ (lane & 7)) << 3;
            uint4 wq = *(const uint4*)&tB[lane * 64 + ph];
            hs += dot8(wq, &ytL[c * 64 + w * 8]);
          }
        }
        paccL[w * 64 + lane] = hs;
        __syncthreads();
        if (t < 64) {
          float hsum = b1[nA + t];
#pragma unroll
          for (int q = 0; q < 8; ++q) hsum += paccL[q * 64 + t];
          float a = tanhf(hsum);
          float ap = 1.f - a * a;
          c1L[t] = ap; c2L[t] = -a * ap;
          asx[nA + t] = a;
        }
        __syncthreads();
        float C1 = c1L[awn + l16], C2 = c2L[awn + l16];
#pragma unroll
        for (int r = 0; r < 4; ++r) {
          int row0 = mX + awm + quad * 4 + r;
          float g0 = acc0[r], g1 = acc1[r];
          tbuf[(size_t)row0 * HID + nA + awn + l16]        = f2bfu(g0 * (C1 + C2 * g0));
          tbuf[(size_t)(row0 + 16) * HID + nA + awn + l16] = f2bfu(g1 * (C1 + C2 * g1));
        }
      }
      xbar(arr, gen, barid++, lead);
      // ========== PHASE B: dDy = t @ W2t^T (K-split 2, fused dy-matvec) ==========
      {
        if (lane < 32)
          GLL16(asx + kb + w * 128 + lane * 4, &asL[w * 128], 1);
        issueB(0, 0); issueB(1, 1); issueB(2, 2);
        issueB(3, 3); issueB(4, 4); issueB(5, 5);
        f32x4 acc = {0.f,0.f,0.f,0.f};
        float dys = 0.f;
#pragma unroll
        for (int c = 0; c < 16; ++c) {
          if (c < 10) issueB((c + 6) & 7, c + 6);
          if (c < 11)      { WAITV(12); }
          else if (c == 11){ WAITV(8); }
          else if (c == 12){ WAITV(6); }
          else if (c == 13){ WAITV(4); }
          else if (c == 14){ WAITV(2); }
          else             { WAITV(0); }
          SBAR();
          const short* tA = &tiles[c & 7][0];
          const short* tB = &tiles[c & 7][4096];
#pragma unroll
          for (int kk = 0; kk < 64; kk += 32) {
            int lg = (kk >> 3) + quad;
            int pa = (bwm + l16), pb = (bwn + l16);
            short8 a = *(const short8*)&tA[pa * 64 + ((lg ^ (pa & 7)) << 3)];
            short8 b = *(const short8*)&tB[pb * 64 + ((lg ^ (pb & 7)) << 3)];
            acc = __builtin_amdgcn_mfma_f32_16x16x32_bf16(a, b, acc, 0, 0, 0);
          }
          if (t < 256) {
            int col = t & 31, seg = t >> 5;
            int ph = (seg ^ (col & 7)) << 3;
            uint4 wq = *(const uint4*)&tB[col * 64 + ph];
            dys += dot8(wq, &asL[c * 64 + seg * 8]);
          }
        }
        __syncthreads();                     // all waves past frag reads
        if (t < 256) paccL[t] = dys;
        __syncthreads();
        float dyown = 0.f;
        if (t < 32) {
#pragma unroll
          for (int q = 0; q < 8; ++q) dyown += paccL[q * 32 + t];
        }
        if (kq == 1) {
          // ship partial (dDy 64x32 + dy 32) to kq==0 peer via XCD L2
          int lrow = bwm + quad * 4, lcol = bwn + l16;
#pragma unroll
          for (int r = 0; r < 4; ++r) rec[(lrow + r) * 32 + lcol] = acc[r];
          if (t < 32) rec[2048 + t] = dyown;
          asm volatile("s_waitcnt vmcnt(0)" ::: "memory");
          __syncthreads();
          if (t == 0)
            __hip_atomic_store(flg, seq, __ATOMIC_RELAXED, __HIP_MEMORY_SCOPE_AGENT);
        } else {
          if (t == 0) {
            while (__hip_atomic_load(flg, __ATOMIC_RELAXED, __HIP_MEMORY_SCOPE_AGENT) < seq)
              __builtin_amdgcn_s_sleep(1);
          }
          __syncthreads();
          float* pLDS = (float*)&tiles[0][0];   // ring drained; reuse as staging
          GLL16(rec + w * 256 + lane * 4, pLDS + w * 256, 1);
          if (w == 0) GLL4(rec + 2048 + lane, pLDS + 2048, 1);
          WAITV(0);
          __syncthreads();
          int lrow = bwm + quad * 4, lcol = bwn + l16;
          f32x4 o = acc;
#pragma unroll
          for (int r = 0; r < 4; ++r) o[r] += pLDS[(lrow + r) * 32 + lcol];
          if (st == 0) K1 = o; else if (st == 1) K2 = o; else if (st == 2) K3 = o;
          if (st < 3) {
#pragma unroll
            for (int r = 0; r < 4; ++r) {
              float v = DyR[r] + cn * o[r];
              Vbuf[(size_t)(erow0 + r) * DIM + ecol] = f2bfu(v);
            }
          } else {
            const float dt6 = DT / 6.f;
#pragma unroll
            for (int r = 0; r < 4; ++r) {
              float v = DyR[r] + dt6 * (K1[r] + 2.f * K2[r] + 2.f * K3[r] + o[r]);
              DyR[r] = v;
              Vbuf[(size_t)(erow0 + r) * DIM + ecol] = f2bfu(v);
              if (ss & 1) out[(size_t)(ss / 2 + 1) * ROWSZ + DIM + (size_t)(erow0 + r) * DIM + ecol] = v;
            }
          }
          if (t < 32) {
            float k4 = dyown + pLDS[2048 + t] + b2[nB + t];
            if (st == 0) kd1 = k4; else if (st == 1) kd2 = k4; else if (st == 2) kd3 = k4;
            if (st < 3) {
              ytx[nB + t] = yR + cn * k4;
            } else {
              yR += (DT / 6.f) * (kd1 + 2.f * kd2 + 2.f * kd3 + k4);
              ytx[nB + t] = yR;
              if ((ss & 1) && xcd == 0) out[(size_t)(ss / 2 + 1) * ROWSZ + nB + t] = yR;
            }
          }
        }
      }
      xbar(arr, gen, barid++, lead);
    }
  }
}

extern "C" void kernel_launch(void* const* d_in, const int* in_sizes, int n_in,
                              void* d_out, int out_size, void* d_ws, size_t ws_size,
                              hipStream_t stream) {
  const float* y0  = (const float*)d_in[1];
  const float* Dy0 = (const float*)d_in[2];
  const float* W1  = (const float*)d_in[3];
  const float* b1  = (const float*)d_in[4];
  const float* W2  = (const float*)d_in[5];
  const float* b2  = (const float*)d_in[6];
  float* out = (float*)d_out;

  char* p = (char*)d_ws;
  auto alloc = [&](size_t bytes) {
    char* r = p;
    p += (bytes + 255) & ~(size_t)255;
    return r;
  };
  unsigned short* W1t  = (unsigned short*)alloc((size_t)HID * DIM * 2);
  unsigned short* W2t  = (unsigned short*)alloc((size_t)DIM * HID * 2);
  unsigned short* Vbuf = (unsigned short*)alloc((size_t)DIM * DIM * 2);
  unsigned short* tbuf = (unsigned short*)alloc((size_t)DIM * HID * 2);
  float* yts  = (float*)alloc(8 * DIM * 4);
  float* a_ss = (float*)alloc(8 * HID * 4);
  float* pbuf = (float*)alloc((size_t)8 * 16 * 2112 * 4);
  int* ctrl   = (int*)alloc(8192);

  hipMemsetAsync(ctrl, 0, 8192, stream);
  k_transpose_bf16<<<dim3(HID / 32, DIM / 32), 256, 0, stream>>>(W1, (__hip_bfloat16*)W1t, DIM, HID);
  k_transpose_bf16<<<dim3(DIM / 32, HID / 32), 256, 0, stream>>>(W2, (__hip_bfloat16*)W2t, HID, DIM);
  k_persist<<<256, 512, 0, stream>>>(y0, Dy0, W1t, W2t, b1, b2,
                                     Vbuf, tbuf, yts, a_ss, pbuf, ctrl, out);
}

// Round 10
// 863.893 us; speedup vs baseline: 1.4487x; 1.4487x over previous
//
#include <hip/hip_runtime.h>
#include <hip/hip_bf16.h>

typedef __attribute__((ext_vector_type(8))) short short8;
typedef float f32x4 __attribute__((ext_vector_type(4)));

#define DIM 512
#define HID 2048
#define ROWSZ (513*512)
#define DT 0.0625f

#define WAITV(n) asm volatile("s_waitcnt vmcnt(" #n ")" ::: "memory")
#define SBAR()   asm volatile("s_barrier" ::: "memory")
typedef const __attribute__((address_space(1))) void* gas1;
typedef __attribute__((address_space(3))) void* las3;
// aux=1 -> SC0: bypass L1, served by XCD L2 (mutable); aux=0 -> one-time weight loads
#define GLL16(g,l,aux) __builtin_amdgcn_global_load_lds((gas1)(g),(las3)(l),16,0,aux)
#define GLL4(g,l,aux)  __builtin_amdgcn_global_load_lds((gas1)(g),(las3)(l),4,0,aux)

__device__ __forceinline__ float bf2f(unsigned short s){ return __uint_as_float(((unsigned)s)<<16); }
__device__ __forceinline__ unsigned short f2bfu(float f){ __hip_bfloat16 h=__float2bfloat16(f); return *(unsigned short*)&h; }
__device__ __forceinline__ float dot8(uint4 wq, const float* a){
  const unsigned short* ws=(const unsigned short*)&wq;
  float s=0.f;
#pragma unroll
  for(int i=0;i<8;++i) s += bf2f(ws[i])*a[i];
  return s;
}
__device__ __forceinline__ float dot8bb(uint4 wq, const unsigned short* a){
  const unsigned short* ws=(const unsigned short*)&wq;
  float s=0.f;
#pragma unroll
  for(int i=0;i<8;++i) s += bf2f(ws[i])*bf2f(a[i]);
  return s;
}

// XCD barrier: 32 wgs, relaxed agent atomics, no cache maintenance
__device__ __forceinline__ void xbar(int* arr, int* gen, int target, bool lead){
  asm volatile("s_waitcnt vmcnt(0) lgkmcnt(0)" ::: "memory");
  __syncthreads();
  if (threadIdx.x == 0){
    __hip_atomic_fetch_add(arr, 1, __ATOMIC_RELAXED, __HIP_MEMORY_SCOPE_AGENT);
    if (lead){
      while (__hip_atomic_load(arr, __ATOMIC_RELAXED, __HIP_MEMORY_SCOPE_AGENT) < 32*target)
        __builtin_amdgcn_s_sleep(2);
      __hip_atomic_store(gen, target, __ATOMIC_RELAXED, __HIP_MEMORY_SCOPE_AGENT);
    } else {
      while (__hip_atomic_load(gen, __ATOMIC_RELAXED, __HIP_MEMORY_SCOPE_AGENT) < target)
        __builtin_amdgcn_s_sleep(4);
    }
  }
  __syncthreads();
}

__global__ void k_transpose_bf16(const float* __restrict__ src,
                                 __hip_bfloat16* __restrict__ dst, int R, int C) {
  __shared__ float tile[32][33];
  int c0 = blockIdx.x * 32, r0 = blockIdx.y * 32;
  int tx = threadIdx.x & 31, ty = threadIdx.x >> 5;
  for (int i = 0; i < 32; i += 8)
    tile[ty + i][tx] = src[(size_t)(r0 + ty + i) * C + c0 + tx];
  __syncthreads();
  for (int i = 0; i < 32; i += 8)
    dst[(size_t)(c0 + ty + i) * R + r0 + tx] = __float2bfloat16(tile[tx][ty + i]);
}

__global__ __launch_bounds__(512, 1) void k_persist(
    const float* __restrict__ y0, const float* __restrict__ Dy0,
    const unsigned short* __restrict__ W1t, const unsigned short* __restrict__ W2t,
    const float* __restrict__ b1, const float* __restrict__ b2,
    unsigned short* __restrict__ Vbuf, unsigned short* __restrict__ tbuf,
    float* __restrict__ yts, unsigned short* __restrict__ a_ss, float* __restrict__ pbuf,
    int* __restrict__ ctrl, float* __restrict__ out) {
  __shared__ __align__(16) short W1L[64 * 512];    // 64 KB: wg's 64 W1 cols, K=512, swizzled
  __shared__ __align__(16) short W2L[32 * 1024];   // 64 KB: wg's 32 W2t rows, K-half, swizzled
  __shared__ __align__(16) short ring[3][4096];    // 24 KB: A-tile ring, 64x64 chunks
  __shared__ float ytL[DIM];                       // 2 KB
  __shared__ __align__(16) unsigned short asL[1024]; // 2 KB (bf16 a, K-half)
  __shared__ float pacc[512];                      // 2 KB
  __shared__ float c1L[64], c2L[64];               // 0.5 KB
  __shared__ int bcast[2];
  // total ~162.3 KB -> 1 wg/CU -> exactly 32 wg/XCD

  const int t = threadIdx.x;
  if (t == 0) {
    int x;
    asm volatile("s_getreg_b32 %0, hwreg(HW_REG_XCC_ID)" : "=s"(x));
    x &= 7;
    bcast[0] = x;
    bcast[1] = atomicAdd(&ctrl[x], 1);
  }
  __syncthreads();
  const int xcd = bcast[0];
  const int sl  = bcast[1] & 31;
  const bool lead = (sl == 0);
  int* arr = ctrl + 64 + xcd * 64;
  int* gen = arr + 32;

  const int w = t >> 6, lane = t & 63, quad = lane >> 4, l16 = lane & 15;
  const int r8 = lane >> 3;
  const int mX = xcd * 64;
  const int nA = sl * 64;                 // phase A: wg's 64 hidden cols
  const int ni = sl >> 1, kq = sl & 1;    // phase B: 16 n-tiles x 2 K-halves
  const int nB = ni * 32;
  const int kb = kq * 1024;
  float* ytx = yts + xcd * DIM;
  unsigned short* asx = a_ss + xcd * HID;
  float* rec = pbuf + (size_t)(xcd * 16 + ni) * 2112;
  int* flg = ctrl + 576 + xcd * 16 + ni;

  const int awm = (w & 1) * 32, awn = (w >> 1) * 16;   // phase A: 2m x 4n waves
  const int bwm = (w >> 1) * 16, bwn = (w & 1) * 16;   // phase B: 4m x 2n waves

  f32x4 DyR = {0.f,0.f,0.f,0.f}, K1 = DyR, K2 = DyR, K3 = DyR;
  float yR = 0.f, kd1 = 0.f, kd2 = 0.f, kd3 = 0.f;
  const int erow0 = mX + bwm + quad * 4;
  const int ecol  = nB + bwn + l16;

  auto issueA = [&](int buf, int c) {
    int k0 = c * 64;
    GLL16(Vbuf + (size_t)(mX + w * 8 + r8) * DIM + k0 + (((lane & 7) ^ r8) << 3),
          &ring[buf][(w * 8) * 64], 1);
  };
  auto issueB = [&](int buf, int c) {
    int k0 = kb + c * 64;
    GLL16(tbuf + (size_t)(mX + w * 8 + r8) * HID + k0 + (((lane & 7) ^ r8) << 3),
          &ring[buf][(w * 8) * 64], 1);
  };

  // ---- one-time: weights -> LDS (swizzled: physical granule p holds logical (p&~7)|((p&7)^(r&7))) ----
#pragma unroll
  for (int i = 0; i < 8; ++i) {
    int r = w * 8 + i;
    int src = ((lane & ~7) | ((lane & 7) ^ (r & 7))) << 3;
    GLL16(W1t + (size_t)(nA + r) * DIM + src, &W1L[r * 512], 0);
  }
#pragma unroll
  for (int i = 0; i < 4; ++i) {
    int r = w * 4 + i;
#pragma unroll
    for (int h2 = 0; h2 < 2; ++h2) {
      int g0 = h2 * 64 + lane;
      int src = ((g0 & ~7) | ((g0 & 7) ^ (r & 7))) << 3;
      GLL16(W2t + (size_t)(nB + r) * HID + kb + src, &W2L[r * 1024 + h2 * 512], 0);
    }
  }
  // ---- init state ----
  if (kq == 0) {
#pragma unroll
    for (int r = 0; r < 4; ++r) {
      float v = Dy0[(size_t)(erow0 + r) * DIM + ecol];
      DyR[r] = v;
      Vbuf[(size_t)(erow0 + r) * DIM + ecol] = f2bfu(v);
      out[DIM + (size_t)(erow0 + r) * DIM + ecol] = v;
    }
    if (t < 32) {
      float v = y0[nB + t];
      yR = v;
      ytx[nB + t] = v;
      if (xcd == 0) out[nB + t] = v;
    }
  }
  WAITV(0);
  __syncthreads();
  int barid = 1;
  xbar(arr, gen, barid++, lead);

  for (int ss = 0; ss < 16; ++ss) {
    for (int st = 0; st < 4; ++st) {
      const float cn = (st == 2) ? DT : 0.5f * DT;
      const int seq = ss * 4 + st + 1;
      // ========== PHASE A: g = V @ W1^T (W1 resident), h-matvec from resident tile ==========
      {
        GLL4(ytx + w * 64 + lane, &ytL[w * 64], 1);      // oldest load
        issueA(0, 0); issueA(1, 1);
        WAITV(2); SBAR();                                 // ytL landed (all waves)
        // h-dot: 64 rows x 8 segs, resident W1L
        {
          int row = t & 63, seg = t >> 6;
          float hs = 0.f;
#pragma unroll
          for (int g = 0; g < 8; ++g) {
            int lg = seg * 8 + g;
            int ps = ((lg & ~7) | ((lg & 7) ^ (row & 7))) << 3;
            hs += dot8(*(const uint4*)&W1L[row * 512 + ps], &ytL[lg * 8]);
          }
          pacc[seg * 64 + row] = hs;
        }
        __syncthreads();
        if (t < 64) {
          float hsum = b1[nA + t];
#pragma unroll
          for (int q = 0; q < 8; ++q) hsum += pacc[q * 64 + t];
          float a = tanhf(hsum);
          float ap = 1.f - a * a;
          c1L[t] = ap; c2L[t] = -a * ap;
          asx[nA + t] = f2bfu(a);
        }
        f32x4 acc0 = {0.f,0.f,0.f,0.f}, acc1 = acc0;
#pragma unroll
        for (int c = 0; c < 8; ++c) {
          if (c < 7) { WAITV(1); } else { WAITV(0); }
          SBAR();
          if (c < 6) issueA((c + 2) % 3, c + 2);
          const short* tA = ring[c % 3];
#pragma unroll
          for (int kk = 0; kk < 64; kk += 32) {
            int lg = (kk >> 3) + quad;
            int pa0 = awm + l16, pa1 = awm + 16 + l16, pb = awn + l16;
            short8 a0 = *(const short8*)&tA[pa0 * 64 + ((lg ^ (pa0 & 7)) << 3)];
            short8 a1 = *(const short8*)&tA[pa1 * 64 + ((lg ^ (pa1 & 7)) << 3)];
            int gb = c * 8 + lg;
            short8 b = *(const short8*)&W1L[pb * 512 + (((gb & ~7) | ((gb & 7) ^ (pb & 7))) << 3)];
            acc0 = __builtin_amdgcn_mfma_f32_16x16x32_bf16(a0, b, acc0, 0, 0, 0);
            acc1 = __builtin_amdgcn_mfma_f32_16x16x32_bf16(a1, b, acc1, 0, 0, 0);
          }
        }
        int row0 = mX + awm + quad * 4;
        int coln = nA + awn + l16;
        float C1 = c1L[awn + l16], C2 = c2L[awn + l16];
#pragma unroll
        for (int r = 0; r < 4; ++r) {
          float g0 = acc0[r], g1 = acc1[r];
          tbuf[(size_t)(row0 + r) * HID + coln]      = f2bfu(g0 * (C1 + C2 * g0));
          tbuf[(size_t)(row0 + 16 + r) * HID + coln] = f2bfu(g1 * (C1 + C2 * g1));
        }
      }
      xbar(arr, gen, barid++, lead);
      // ========== PHASE B: dDy = t @ W2 (W2 resident, K-split 2), dy-matvec resident ==========
      {
        GLL4((const unsigned short*)asx + kb + w * 128 + lane * 2, &asL[w * 128], 1);
        issueB(0, 0); issueB(1, 1);
        WAITV(2); SBAR();                                 // asL landed
        // dy-dot: 32 rows x 16 segs over K-half
        {
          int row = t & 31, seg = t >> 5;
          float ds = 0.f;
#pragma unroll
          for (int g = 0; g < 8; ++g) {
            int lg = seg * 8 + g;
            int ps = ((lg & ~7) | ((lg & 7) ^ (row & 7))) << 3;
            ds += dot8bb(*(const uint4*)&W2L[row * 1024 + ps], &asL[lg * 8]);
          }
          pacc[seg * 32 + row] = ds;
        }
        __syncthreads();
        float dyown = 0.f;
        if (t < 32) {
#pragma unroll
          for (int q = 0; q < 16; ++q) dyown += pacc[q * 32 + t];
        }
        f32x4 acc = {0.f,0.f,0.f,0.f};
#pragma unroll
        for (int c = 0; c < 16; ++c) {
          if (c < 15) { WAITV(1); } else { WAITV(0); }
          SBAR();
          if (c < 14) issueB((c + 2) % 3, c + 2);
          const short* tA = ring[c % 3];
#pragma unroll
          for (int kk = 0; kk < 64; kk += 32) {
            int lg = (kk >> 3) + quad;
            int pa = bwm + l16, pb = bwn + l16;
            short8 a = *(const short8*)&tA[pa * 64 + ((lg ^ (pa & 7)) << 3)];
            int gb = c * 8 + lg;
            short8 b = *(const short8*)&W2L[pb * 1024 + (((gb & ~7) | ((gb & 7) ^ (pb & 7))) << 3)];
            acc = __builtin_amdgcn_mfma_f32_16x16x32_bf16(a, b, acc, 0, 0, 0);
          }
        }
        if (kq == 1) {
          int lrow = bwm + quad * 4, lcol = bwn + l16;
#pragma unroll
          for (int r = 0; r < 4; ++r) rec[(lrow + r) * 32 + lcol] = acc[r];
          if (t < 32) rec[2048 + t] = dyown;
          asm volatile("s_waitcnt vmcnt(0)" ::: "memory");
          __syncthreads();
          if (t == 0)
            __hip_atomic_store(flg, seq, __ATOMIC_RELAXED, __HIP_MEMORY_SCOPE_AGENT);
        } else {
          if (t == 0) {
            while (__hip_atomic_load(flg, __ATOMIC_RELAXED, __HIP_MEMORY_SCOPE_AGENT) < seq)
              __builtin_amdgcn_s_sleep(1);
          }
          __syncthreads();
          float* pLDS = (float*)&ring[0][0];     // ring drained; reuse
          GLL16(rec + w * 256 + lane * 4, pLDS + w * 256, 1);
          if (w == 0) GLL4(rec + 2048 + lane, pLDS + 2048, 1);
          WAITV(0);
          __syncthreads();
          int lrow = bwm + quad * 4, lcol = bwn + l16;
          f32x4 o = acc;
#pragma unroll
          for (int r = 0; r < 4; ++r) o[r] += pLDS[(lrow + r) * 32 + lcol];
          if (st == 0) K1 = o; else if (st == 1) K2 = o; else if (st == 2) K3 = o;
          if (st < 3) {
#pragma unroll
            for (int r = 0; r < 4; ++r) {
              float v = DyR[r] + cn * o[r];
              Vbuf[(size_t)(erow0 + r) * DIM + ecol] = f2bfu(v);
            }
          } else {
            const float dt6 = DT / 6.f;
#pragma unroll
            for (int r = 0; r < 4; ++r) {
              float v = DyR[r] + dt6 * (K1[r] + 2.f * K2[r] + 2.f * K3[r] + o[r]);
              DyR[r] = v;
              Vbuf[(size_t)(erow0 + r) * DIM + ecol] = f2bfu(v);
              if (ss & 1) out[(size_t)(ss / 2 + 1) * ROWSZ + DIM + (size_t)(erow0 + r) * DIM + ecol] = v;
            }
          }
          if (t < 32) {
            float k4 = dyown + pLDS[2048 + t] + b2[nB + t];
            if (st == 0) kd1 = k4; else if (st == 1) kd2 = k4; else if (st == 2) kd3 = k4;
            if (st < 3) {
              ytx[nB + t] = yR + cn * k4;
            } else {
              yR += (DT / 6.f) * (kd1 + 2.f * kd2 + 2.f * kd3 + k4);
              ytx[nB + t] = yR;
              if ((ss & 1) && xcd == 0) out[(size_t)(ss / 2 + 1) * ROWSZ + nB + t] = yR;
            }
          }
        }
      }
      xbar(arr, gen, barid++, lead);
    }
  }
}

extern "C" void kernel_launch(void* const* d_in, const int* in_sizes, int n_in,
                              void* d_out, int out_size, void* d_ws, size_t ws_size,
                              hipStream_t stream) {
  const float* y0  = (const float*)d_in[1];
  const float* Dy0 = (const float*)d_in[2];
  const float* W1  = (const float*)d_in[3];
  const float* b1  = (const float*)d_in[4];
  const float* W2  = (const float*)d_in[5];
  const float* b2  = (const float*)d_in[6];
  float* out = (float*)d_out;

  char* p = (char*)d_ws;
  auto alloc = [&](size_t bytes) {
    char* r = p;
    p += (bytes + 255) & ~(size_t)255;
    return r;
  };
  unsigned short* W1t  = (unsigned short*)alloc((size_t)HID * DIM * 2);
  unsigned short* W2t  = (unsigned short*)alloc((size_t)DIM * HID * 2);
  unsigned short* Vbuf = (unsigned short*)alloc((size_t)DIM * DIM * 2);
  unsigned short* tbuf = (unsigned short*)alloc((size_t)DIM * HID * 2);
  float* yts  = (float*)alloc(8 * DIM * 4);
  unsigned short* a_ss = (unsigned short*)alloc(8 * HID * 2);
  float* pbuf = (float*)alloc((size_t)8 * 16 * 2112 * 4);
  int* ctrl   = (int*)alloc(8192);

  hipMemsetAsync(ctrl, 0, 8192, stream);
  k_transpose_bf16<<<dim3(HID / 32, DIM / 32), 256, 0, stream>>>(W1, (__hip_bfloat16*)W1t, DIM, HID);
  k_transpose_bf16<<<dim3(DIM / 32, HID / 32), 256, 0, stream>>>(W2, (__hip_bfloat16*)W2t, HID, DIM);
  k_persist<<<256, 512, 0, stream>>>(y0, Dy0, W1t, W2t, b1, b2,
                                     Vbuf, tbuf, yts, a_ss, pbuf, ctrl, out);
}